// Round 9
// baseline (251.594 us; speedup 1.0000x reference)
//
#include <hip/hip_runtime.h>
#include <hip/hip_bf16.h>

#define BS_   4096
#define NQ_   21
#define NK_   7
#define E_    512
#define MQ_   (BS_*NQ_)   // 86016 q rows
#define MK_   (BS_*NK_)   // 28672 k rows
#define MT1_  (MQ_/128)   // 672 q block-rows
#define MT2_  (MK_/128)   // 224 k block-rows
#define SCALE_ 2.88539008177792681f   // 2*log2(e): exp2(SCALE*x) = e^{2x}

typedef __attribute__((ext_vector_type(8))) short bf16x8;
typedef __attribute__((ext_vector_type(4))) float f32x4;
typedef __attribute__((ext_vector_type(8))) unsigned short u16x8;

__device__ __forceinline__ unsigned int cvt_pk_bf16(float lo, float hi){
  unsigned int r;
  asm("v_cvt_pk_bf16_f32 %0, %1, %2" : "=v"(r) : "v"(lo), "v"(hi));
  return r;
}
__device__ __forceinline__ float bf2f(unsigned short h){
  return __builtin_bit_cast(float, (unsigned int)h << 16);
}
__device__ __forceinline__ void gload_lds16(const void* g, void* l){
  __builtin_amdgcn_global_load_lds(
      (const __attribute__((address_space(1))) unsigned int*)g,
      (__attribute__((address_space(3))) unsigned int*)l, 16, 0, 0);
}

// ---------------- weight cast f32 -> bf16 ----------------
__global__ __launch_bounds__(256) void cast_weights(
    const float* __restrict__ wq, const float* __restrict__ wk,
    unsigned int* __restrict__ oq, unsigned int* __restrict__ ok)
{
  int i = blockIdx.x * 256 + threadIdx.x;           // 65536 float4s each
  float4 a = ((const float4*)wq)[i];
  float4 b = ((const float4*)wk)[i];
  uint2 ua = { cvt_pk_bf16(a.x, a.y), cvt_pk_bf16(a.z, a.w) };
  uint2 ub = { cvt_pk_bf16(b.x, b.y), cvt_pk_bf16(b.z, b.w) };
  ((uint2*)oq)[i] = ua;
  ((uint2*)ok)[i] = ub;
}

// ---------------- merged projection GEMMs, all-bf16 LDS ---------------------
// C[m,h] = (sum_e A[m,e]*W[h,e] + bias[h]) * SCALE, bf16 out.
// 128x128 tile, BK=32, 16 K-steps, 4 waves (2x2), double-buffered.
// Both LDS tiles are bf16 [128 rows][64 B], swizzle ^(((row>>1)&3)<<4)
// (conflict-free pattern verified in rounds 5/8 for the B tile):
//   A: reg-staged (coalesced float4 loads -> cvt_pk -> swizzled ds_write_b64)
//   B: global_load_lds DMA with pre-swizzled global source (rule #21)
// LDS = 2*(8+8) KB = 32 KB -> 4+ blocks/CU (VGPR-capped at 4 via launch_bounds).
__global__ __launch_bounds__(256, 4)
void gemm_proj(const float* __restrict__ Aq, const float* __restrict__ Ak,
               const unsigned short* __restrict__ Bq, const unsigned short* __restrict__ Bk,
               const float* __restrict__ bq, const float* __restrict__ bk,
               unsigned short* __restrict__ Cq, unsigned short* __restrict__ Ck)
{
  __shared__ char Asm[2][128 * 64];   // 8 KB each: bf16 A-tile
  __shared__ char Bsm[2][128 * 64];   // 8 KB each: bf16 B-tile

  const int tid  = threadIdx.x;
  const int lane = tid & 63;
  const int w    = tid >> 6;
  const int wr   = w >> 1, wc = w & 1;

  // XCD-grouped bijection (3584 blocks % 8 == 0): nt fastest per XCD.
  const int orig = (int)blockIdx.x;
  const int j    = orig >> 3;
  int       mt   = (j >> 2) * 8 + (orig & 7);
  const int nt   = j & 3;

  const float* A; const unsigned short* Bw; const float* bias; unsigned short* C;
  if (mt < MT1_){ A = Aq; Bw = Bq; bias = bq; C = Cq; }
  else          { A = Ak; Bw = Bk; bias = bk; C = Ck; mt -= MT1_; }

  const long m0 = (long)mt << 7;
  const int  n0 = nt << 7;
  const char* Abyte = (const char*)(A + m0 * E_);
  const char* Bbyte = (const char*)Bw;

  // ---- A staging map: 4 x 16B-f32-in -> 8B-bf16-out per thread per K-step
  long asrc[4]; int adst[4];
#pragma unroll
  for (int i = 0; i < 4; ++i){
    const int c   = tid + i * 256;            // in-chunk 0..1023 (16 B f32)
    const int row = c >> 3;                   // 8 chunks per 128-B f32 row
    const int sl  = c & 7;
    asrc[i] = (long)row * (E_ * 4) + sl * 16; // plain (unswizzled) source
    adst[i] = row * 64 + (((sl & 6) * 8) ^ (((row >> 1) & 3) << 4)) + (sl & 1) * 8;
  }
  // ---- B staging map: 2 x 16B DMA per thread per K-step (pre-swizzled src)
  long bsrc[2]; int bdst[2];
#pragma unroll
  for (int i = 0; i < 2; ++i){
    const int c   = tid + i * 256;            // chunk 0..511
    const int row = c >> 2;                   // 4 chunks per 64-B row
    const int sl  = c & 3;
    bsrc[i] = (long)(n0 + row) * (E_ * 2) + ((sl * 16) ^ (((row >> 1) & 3) << 4));
    bdst[i] = c * 16;
  }

  // ---- fragment-read byte offsets (loop-invariant, conflict-free pattern)
  int aoff[4], boff[4];
#pragma unroll
  for (int m = 0; m < 4; ++m){
    const int r = wr * 64 + m * 16 + (lane & 15);
    aoff[m] = r * 64 + ((16 * (lane >> 4)) ^ (((r >> 1) & 3) << 4));
  }
#pragma unroll
  for (int n = 0; n < 4; ++n){
    const int r = wc * 64 + n * 16 + (lane & 15);
    boff[n] = r * 64 + ((16 * (lane >> 4)) ^ (((r >> 1) & 3) << 4));
  }

  f32x4 acc[4][4];
  const f32x4 z4 = {0.f, 0.f, 0.f, 0.f};
#pragma unroll
  for (int m = 0; m < 4; ++m)
#pragma unroll
    for (int n = 0; n < 4; ++n) acc[m][n] = z4;

  // ---- prologue: stage K-step 0 into buffer 0
  {
    float4 av[4];
#pragma unroll
    for (int i = 0; i < 4; ++i) av[i] = *(const float4*)(Abyte + asrc[i]);
#pragma unroll
    for (int i = 0; i < 2; ++i) gload_lds16(Bbyte + bsrc[i], Bsm[0] + bdst[i]);
#pragma unroll
    for (int i = 0; i < 4; ++i){
      uint2 u = { cvt_pk_bf16(av[i].x, av[i].y), cvt_pk_bf16(av[i].z, av[i].w) };
      *(uint2*)(Asm[0] + adst[i]) = u;
    }
  }
  __syncthreads();

  // ---- main loop: 16 K-steps of 32
#pragma unroll 2
  for (int t = 0; t < 16; ++t){
    const int buf = t & 1, nbuf = buf ^ 1;
    float4 av[4];
    if (t < 15){
      const long ka = (long)(t + 1) * 128;    // A f32 k-window advance (bytes)
      const long kb = (long)(t + 1) * 64;     // B bf16 k-window advance (bytes)
#pragma unroll
      for (int i = 0; i < 4; ++i) av[i] = *(const float4*)(Abyte + asrc[i] + ka);
#pragma unroll
      for (int i = 0; i < 2; ++i) gload_lds16(Bbyte + bsrc[i] + kb, Bsm[nbuf] + bdst[i]);
    }
    // compute on buf
    bf16x8 af[4], bfr[4];
#pragma unroll
    for (int m = 0; m < 4; ++m) af[m]  = *(const bf16x8*)(Asm[buf] + aoff[m]);
#pragma unroll
    for (int n = 0; n < 4; ++n) bfr[n] = *(const bf16x8*)(Bsm[buf] + boff[n]);
#pragma unroll
    for (int m = 0; m < 4; ++m)
#pragma unroll
      for (int n = 0; n < 4; ++n)
        acc[m][n] = __builtin_amdgcn_mfma_f32_16x16x32_bf16(af[m], bfr[n], acc[m][n], 0, 0, 0);
    if (t < 15){
#pragma unroll
      for (int i = 0; i < 4; ++i){
        uint2 u = { cvt_pk_bf16(av[i].x, av[i].y), cvt_pk_bf16(av[i].z, av[i].w) };
        *(uint2*)(Asm[nbuf] + adst[i]) = u;
      }
    }
    __syncthreads();
  }

  // ---- epilogue: v = (acc + bias)*SCALE, bf16 store
  // C/D layout: col = lane&15 (+n*16), row = (lane>>4)*4 + j
  const int ccol0 = n0 + wc * 64 + (lane & 15);
  float bvs[4];
#pragma unroll
  for (int n = 0; n < 4; ++n) bvs[n] = bias[ccol0 + n * 16] * SCALE_;
#pragma unroll
  for (int m = 0; m < 4; ++m){
    const long rbase = m0 + wr * 64 + m * 16 + (lane >> 4) * 4;
#pragma unroll
    for (int n = 0; n < 4; ++n){
      const long col = ccol0 + n * 16;
      float v0 = fmaf(acc[m][n][0], SCALE_, bvs[n]);
      float v1 = fmaf(acc[m][n][1], SCALE_, bvs[n]);
      float v2 = fmaf(acc[m][n][2], SCALE_, bvs[n]);
      float v3 = fmaf(acc[m][n][3], SCALE_, bvs[n]);
      unsigned int u01 = cvt_pk_bf16(v0, v1);
      unsigned int u23 = cvt_pk_bf16(v2, v3);
      C[(rbase + 0) * E_ + col] = (unsigned short)(u01 & 0xffffu);
      C[(rbase + 1) * E_ + col] = (unsigned short)(u01 >> 16);
      C[(rbase + 2) * E_ + col] = (unsigned short)(u23 & 0xffffu);
      C[(rbase + 3) * E_ + col] = (unsigned short)(u23 >> 16);
    }
  }
}

// ---------------- fused score + softmax + weighted sum ----------------
// One WAVE per batch. q'', k'' are bf16 pre-scaled by 2*log2(e).
// score(q,k) = sum_h wv_h * tanh(q+k) = Wsum - 2*sum_h wv_h / (1 + e^{2(q+k)})
__global__ __launch_bounds__(256, 2)
void attn_fused(const unsigned short* __restrict__ qp,
                const unsigned short* __restrict__ kp,
                const float* __restrict__ keys,
                const float* __restrict__ wv, const float* __restrict__ wvb,
                const int* __restrict__ mask,
                float* __restrict__ out0, float* __restrict__ out1)
{
  const int lane = threadIdx.x & 63;
  const int b    = blockIdx.x * 4 + (threadIdx.x >> 6);

  // per-lane wv slice (h = lane*8 .. +7)
  float wvr[8];
  *(float4*)&wvr[0] = ((const float4*)wv)[lane * 2];
  *(float4*)&wvr[4] = ((const float4*)wv)[lane * 2 + 1];

  // k'' rows -> f32 regs [7][8]
  float kf[NK_][8];
#pragma unroll
  for (int k = 0; k < NK_; ++k){
    u16x8 u = *(const u16x8*)(kp + ((long)b * NK_ + k) * E_ + lane * 8);
#pragma unroll
    for (int j = 0; j < 8; ++j) kf[k][j] = bf2f((unsigned short)u[j]);
  }
  // raw keys -> f32 regs [7][8]
  float kr[NK_][8];
#pragma unroll
  for (int k = 0; k < NK_; ++k){
    const float4* p = (const float4*)(keys + ((long)b * NK_ + k) * E_ + lane * 8);
    *(float4*)&kr[k][0] = p[0];
    *(float4*)&kr[k][4] = p[1];
  }

  // Wsum = sum_h wv_h (butterfly over lanes)
  float wsum = ((wvr[0] + wvr[1]) + (wvr[2] + wvr[3])) + ((wvr[4] + wvr[5]) + (wvr[6] + wvr[7]));
#pragma unroll
  for (int off = 32; off; off >>= 1) wsum += __shfl_xor(wsum, off, 64);

  const float vb = wvb[0];
  float base[NK_];
#pragma unroll
  for (int k = 0; k < NK_; ++k)
    base[k] = (wsum + vb) + (float)mask[b * NK_ + k] * (-1e9f);   // fp32 absorption == ref

  const unsigned short* qrow = qp + (long)b * NQ_ * E_ + lane * 8;
  u16x8 qv = *(const u16x8*)qrow;

  float4* o0 = (float4*)(out0 + (long)b * NQ_ * E_) + lane * 2;
  float*  o1 = out1 + (long)b * (NQ_ * NK_);

  for (int qi = 0; qi < NQ_; ++qi){
    // prefetch next q row (hides HBM latency under this iteration's compute)
    u16x8 qn = qv;
    if (qi < NQ_ - 1) qn = *(const u16x8*)(qrow + (qi + 1) * E_);

    float qf[8];
#pragma unroll
    for (int j = 0; j < 8; ++j) qf[j] = bf2f((unsigned short)qv[j]);
    qv = qn;

    // hot loop: 7 independent accumulator chains
    float acc[NK_];
#pragma unroll
    for (int k = 0; k < NK_; ++k){
      float a = 0.f;
#pragma unroll
      for (int j = 0; j < 8; ++j){
        float x = qf[j] + kf[k][j];                  // 2*log2e*(q+k)
        float e = __builtin_amdgcn_exp2f(x);         // e^{2(q+k)}
        float r = __builtin_amdgcn_rcpf(e + 1.0f);   // sigmoid(-2(q+k))
        a = fmaf(wvr[j], r, a);
      }
      acc[k] = a;
    }
    // 7 independent butterflies (chains pipeline)
#pragma unroll
    for (int k = 0; k < NK_; ++k){
      float a = acc[k];
#pragma unroll
      for (int off = 32; off; off >>= 1) a += __shfl_xor(a, off, 64);
      acc[k] = a;
    }
    // scores + 7-wide softmax (all lanes redundantly, registers only)
    float sc[NK_], mx = -3.4e38f;
#pragma unroll
    for (int k = 0; k < NK_; ++k){ sc[k] = fmaf(-2.f, acc[k], base[k]); mx = fmaxf(mx, sc[k]); }
    float sum = 0.f;
#pragma unroll
    for (int k = 0; k < NK_; ++k){ sc[k] = __expf(sc[k] - mx); sum += sc[k]; }
    const float inv = __builtin_amdgcn_rcpf(sum);
    float wgt[NK_];
#pragma unroll
    for (int k = 0; k < NK_; ++k) wgt[k] = sc[k] * inv;

    // attn_weights: lanes 0..6 write wgt[lane] (branchless select)
    float wsel = wgt[0];
#pragma unroll
    for (int k = 1; k < NK_; ++k) wsel = (lane == k) ? wgt[k] : wsel;
    if (lane < NK_) o1[qi * NK_ + lane] = wsel;

    // attn_out = weights @ raw keys (all in registers)
    float4 lo = {0.f,0.f,0.f,0.f}, hi = {0.f,0.f,0.f,0.f};
#pragma unroll
    for (int k = 0; k < NK_; ++k){
      lo.x = fmaf(wgt[k], kr[k][0], lo.x);
      lo.y = fmaf(wgt[k], kr[k][1], lo.y);
      lo.z = fmaf(wgt[k], kr[k][2], lo.z);
      lo.w = fmaf(wgt[k], kr[k][3], lo.w);
      hi.x = fmaf(wgt[k], kr[k][4], hi.x);
      hi.y = fmaf(wgt[k], kr[k][5], hi.y);
      hi.z = fmaf(wgt[k], kr[k][6], hi.z);
      hi.w = fmaf(wgt[k], kr[k][7], hi.w);
    }
    o0[qi * 128 + 0] = lo;
    o0[qi * 128 + 1] = hi;
  }
}

// ---------------- launcher ----------------
extern "C" void kernel_launch(void* const* d_in, const int* in_sizes, int n_in,
                              void* d_out, int out_size, void* d_ws, size_t ws_size,
                              hipStream_t stream)
{
  const float* queries = (const float*)d_in[0];
  const float* keys    = (const float*)d_in[1];
  const float* wq_w    = (const float*)d_in[2];
  const float* wq_b    = (const float*)d_in[3];
  const float* wk_w    = (const float*)d_in[4];
  const float* wk_b    = (const float*)d_in[5];
  const float* wv_w    = (const float*)d_in[6];
  const float* wv_b    = (const float*)d_in[7];
  const int*   mask    = (const int*)d_in[8];
  (void)in_sizes; (void)n_in; (void)out_size; (void)ws_size;

  float* out0 = (float*)d_out;
  float* out1 = out0 + (long)MQ_ * E_;

  char* ws = (char*)d_ws;
  unsigned short* wqb = (unsigned short*)ws;                       // 512 KB
  unsigned short* wkb = (unsigned short*)(ws + 512 * 512 * 2);     // 512 KB
  unsigned short* qb  = (unsigned short*)(ws + (1 << 20));         // 88.1 MB
  unsigned short* kb  = qb + (size_t)MQ_ * E_;                     // 29.4 MB

  cast_weights<<<dim3(256), dim3(256), 0, stream>>>(wq_w, wk_w, (unsigned int*)wqb, (unsigned int*)wkb);
  gemm_proj<<<dim3((MT1_ + MT2_) * 4), dim3(256), 0, stream>>>(
      queries, keys, wqb, wkb, wq_b, wk_b, qb, kb);
  attn_fused<<<dim3(BS_ / 4), dim3(256), 0, stream>>>(qb, kb, keys, wv_w, wv_b, mask, out0, out1);
}

// Round 10
// 248.970 us; speedup vs baseline: 1.0105x; 1.0105x over previous
//
#include <hip/hip_runtime.h>
#include <hip/hip_bf16.h>

#define BS_   4096
#define NQ_   21
#define NK_   7
#define E_    512
#define MQ_   (BS_*NQ_)   // 86016 q rows
#define MK_   (BS_*NK_)   // 28672 k rows
#define MT1_  (MQ_/128)   // 672 q block-rows
#define MT2_  (MK_/128)   // 224 k block-rows
#define SCALE_ 2.88539008177792681f   // 2*log2(e): exp2(SCALE*x) = e^{2x}

typedef __attribute__((ext_vector_type(8))) short bf16x8;
typedef __attribute__((ext_vector_type(4))) float f32x4;
typedef __attribute__((ext_vector_type(8))) unsigned short u16x8;

__device__ __forceinline__ unsigned int cvt_pk_bf16(float lo, float hi){
  unsigned int r;
  asm("v_cvt_pk_bf16_f32 %0, %1, %2" : "=v"(r) : "v"(lo), "v"(hi));
  return r;
}
__device__ __forceinline__ float bf2f(unsigned short h){
  return __builtin_bit_cast(float, (unsigned int)h << 16);
}
__device__ __forceinline__ void gload_lds16(const void* g, void* l){
  __builtin_amdgcn_global_load_lds(
      (const __attribute__((address_space(1))) unsigned int*)g,
      (__attribute__((address_space(3))) unsigned int*)l, 16, 0, 0);
}

// ---------------- weight cast f32 -> bf16 ----------------
__global__ __launch_bounds__(256) void cast_weights(
    const float* __restrict__ wq, const float* __restrict__ wk,
    unsigned int* __restrict__ oq, unsigned int* __restrict__ ok)
{
  int i = blockIdx.x * 256 + threadIdx.x;           // 65536 float4s each
  float4 a = ((const float4*)wq)[i];
  float4 b = ((const float4*)wk)[i];
  uint2 ua = { cvt_pk_bf16(a.x, a.y), cvt_pk_bf16(a.z, a.w) };
  uint2 ub = { cvt_pk_bf16(b.x, b.y), cvt_pk_bf16(b.z, b.w) };
  ((uint2*)oq)[i] = ua;
  ((uint2*)ok)[i] = ub;
}

// ---------------- merged projection GEMMs, counted-vmcnt pipeline -----------
// C[m,h] = (sum_e A[m,e]*W[h,e] + bias[h]) * SCALE, bf16 out.
// 128x128 tile, BK=32, 16 K-steps, 4 waves (2x2).
// 3 LDS buffers, staging issued 2 steps ahead; raw s_barrier + counted
// s_waitcnt vmcnt(N) (T3/T4): loads stay in flight ACROSS barriers, the
// barrier never waits on same-step loads. Per-wave vmem FIFO (6 ops/stage:
// 4 A-f32 loads + 2 B-DMA); loop-top outstanding = [B(t),A(t+1),B(t+1)] = 8,
// vmcnt(2) drains B(t)+A(t+1). A held in regs one iter (avA/avB parity).
// LDS layouts/swizzles identical to round 9 (measured 0 bank conflicts).
__global__ __launch_bounds__(256)
void gemm_proj(const float* __restrict__ Aq, const float* __restrict__ Ak,
               const unsigned short* __restrict__ Bq, const unsigned short* __restrict__ Bk,
               const float* __restrict__ bq, const float* __restrict__ bk,
               unsigned short* __restrict__ Cq, unsigned short* __restrict__ Ck)
{
  __shared__ char Asm[3][128 * 64];   // 8 KB each: bf16 A-tile
  __shared__ char Bsm[3][128 * 64];   // 8 KB each: bf16 B-tile

  const int tid  = threadIdx.x;
  const int lane = tid & 63;
  const int w    = tid >> 6;
  const int wr   = w >> 1, wc = w & 1;

  // XCD-grouped bijection (3584 blocks % 8 == 0): nt fastest per XCD.
  const int orig = (int)blockIdx.x;
  const int j    = orig >> 3;
  int       mt   = (j >> 2) * 8 + (orig & 7);
  const int nt   = j & 3;

  const float* A; const unsigned short* Bw; const float* bias; unsigned short* C;
  if (mt < MT1_){ A = Aq; Bw = Bq; bias = bq; C = Cq; }
  else          { A = Ak; Bw = Bk; bias = bk; C = Ck; mt -= MT1_; }

  const long m0 = (long)mt << 7;
  const int  n0 = nt << 7;
  const char* Abyte = (const char*)(A + m0 * E_);
  const char* Bbyte = (const char*)Bw;

  // ---- A staging map: 4 x 16B-f32-in -> 8B-bf16-out per thread per K-step
  long asrc[4]; int adst[4];
#pragma unroll
  for (int i = 0; i < 4; ++i){
    const int c   = tid + i * 256;            // in-chunk 0..1023 (16 B f32)
    const int row = c >> 3;                   // 8 chunks per 128-B f32 row
    const int sl  = c & 7;
    asrc[i] = (long)row * (E_ * 4) + sl * 16; // plain (unswizzled) source
    adst[i] = row * 64 + (((sl & 6) * 8) ^ (((row >> 1) & 3) << 4)) + (sl & 1) * 8;
  }
  // ---- B staging map: 2 x 16B DMA per thread per K-step (pre-swizzled src)
  long bsrc[2]; int bdst[2];
#pragma unroll
  for (int i = 0; i < 2; ++i){
    const int c   = tid + i * 256;            // chunk 0..511
    const int row = c >> 2;                   // 4 chunks per 64-B row
    const int sl  = c & 3;
    bsrc[i] = (long)(n0 + row) * (E_ * 2) + ((sl * 16) ^ (((row >> 1) & 3) << 4));
    bdst[i] = c * 16;
  }

  // ---- fragment-read byte offsets (loop-invariant, conflict-free pattern)
  int aoff[4], boff[4];
#pragma unroll
  for (int m = 0; m < 4; ++m){
    const int r = wr * 64 + m * 16 + (lane & 15);
    aoff[m] = r * 64 + ((16 * (lane >> 4)) ^ (((r >> 1) & 3) << 4));
  }
#pragma unroll
  for (int n = 0; n < 4; ++n){
    const int r = wc * 64 + n * 16 + (lane & 15);
    boff[n] = r * 64 + ((16 * (lane >> 4)) ^ (((r >> 1) & 3) << 4));
  }

  f32x4 acc[4][4];
  const f32x4 z4 = {0.f, 0.f, 0.f, 0.f};
#pragma unroll
  for (int m = 0; m < 4; ++m)
#pragma unroll
    for (int n = 0; n < 4; ++n) acc[m][n] = z4;

#define STAGE_LOADS(av, T) do { \
  _Pragma("unroll") for (int i_ = 0; i_ < 4; ++i_) \
    av[i_] = *(const float4*)(Abyte + asrc[i_] + (long)(T) * 128); \
} while(0)

#define STAGE_B(BUF, T) do { \
  _Pragma("unroll") for (int i_ = 0; i_ < 2; ++i_) \
    gload_lds16(Bbyte + bsrc[i_] + (long)(T) * 64, Bsm[BUF] + bdst[i_]); \
} while(0)

#define WRITE_A(BUF, av) do { \
  _Pragma("unroll") for (int i_ = 0; i_ < 4; ++i_){ \
    uint2 u_ = { cvt_pk_bf16(av[i_].x, av[i_].y), cvt_pk_bf16(av[i_].z, av[i_].w) }; \
    *(uint2*)(Asm[BUF] + adst[i_]) = u_; \
  } \
} while(0)

#define COMPUTE(BUF) do { \
  bf16x8 af_[4], bfr_[4]; \
  _Pragma("unroll") for (int m_ = 0; m_ < 4; ++m_) af_[m_]  = *(const bf16x8*)(Asm[BUF] + aoff[m_]); \
  _Pragma("unroll") for (int n_ = 0; n_ < 4; ++n_) bfr_[n_] = *(const bf16x8*)(Bsm[BUF] + boff[n_]); \
  _Pragma("unroll") for (int m_ = 0; m_ < 4; ++m_) \
    _Pragma("unroll") for (int n_ = 0; n_ < 4; ++n_) \
      acc[m_][n_] = __builtin_amdgcn_mfma_f32_16x16x32_bf16(af_[m_], bfr_[n_], acc[m_][n_], 0, 0, 0); \
} while(0)

#define BARRIER() do { \
  asm volatile("" ::: "memory"); \
  __builtin_amdgcn_s_barrier(); \
  asm volatile("" ::: "memory"); \
} while(0)

  float4 avA[4], avB[4];

  // ---- prologue: issue stage(0), stage(1); write A(0)
  STAGE_LOADS(avA, 0);  STAGE_B(0, 0);     // A(0)x4, B(0)x2
  STAGE_LOADS(avB, 1);  STAGE_B(1, 1);     // A(1)x4, B(1)x2   (outstanding 12)
  asm volatile("s_waitcnt vmcnt(6)" ::: "memory");   // A(0),B(0) done
  WRITE_A(0, avA);

  // ---- main loop t = 0..13 (steady state; stage(t+2) each iter)
#pragma unroll
  for (int t = 0; t < 14; ++t){
    const int cur = t % 3, nx1 = (t + 1) % 3, nx2 = (t + 2) % 3;
    asm volatile("s_waitcnt vmcnt(2)" ::: "memory"); // drain B(t), A(t+1); B(t+1) stays in flight
    if ((t & 1) == 0) WRITE_A(nx1, avB); else WRITE_A(nx1, avA);
    asm volatile("s_waitcnt lgkmcnt(0)" ::: "memory"); // ds_writes visible before barrier
    BARRIER();                                         // buf[cur] ready for all waves
    if ((t & 1) == 0) STAGE_LOADS(avA, t + 2); else STAGE_LOADS(avB, t + 2);
    STAGE_B(nx2, t + 2);
    COMPUTE(cur);
  }
  // ---- t = 14: no stage(16); A(15) is in avB (loaded at t=13, odd)
  {
    asm volatile("s_waitcnt vmcnt(2)" ::: "memory"); // drain B(14), A(15); B(15) in flight
    WRITE_A(0 /* 15%3 */, avB);
    asm volatile("s_waitcnt lgkmcnt(0)" ::: "memory");
    BARRIER();
    COMPUTE(2 /* 14%3 */);
  }
  // ---- t = 15
  {
    asm volatile("s_waitcnt vmcnt(0)" ::: "memory"); // drain B(15)
    BARRIER();
    COMPUTE(0 /* 15%3 */);
  }

#undef STAGE_LOADS
#undef STAGE_B
#undef WRITE_A
#undef COMPUTE
#undef BARRIER

  // ---- epilogue: v = (acc + bias)*SCALE, bf16 store
  // C/D layout: col = lane&15 (+n*16), row = (lane>>4)*4 + j
  const int ccol0 = n0 + wc * 64 + (lane & 15);
  float bvs[4];
#pragma unroll
  for (int n = 0; n < 4; ++n) bvs[n] = bias[ccol0 + n * 16] * SCALE_;
#pragma unroll
  for (int m = 0; m < 4; ++m){
    const long rbase = m0 + wr * 64 + m * 16 + (lane >> 4) * 4;
#pragma unroll
    for (int n = 0; n < 4; ++n){
      const long col = ccol0 + n * 16;
      float v0 = fmaf(acc[m][n][0], SCALE_, bvs[n]);
      float v1 = fmaf(acc[m][n][1], SCALE_, bvs[n]);
      float v2 = fmaf(acc[m][n][2], SCALE_, bvs[n]);
      float v3 = fmaf(acc[m][n][3], SCALE_, bvs[n]);
      unsigned int u01 = cvt_pk_bf16(v0, v1);
      unsigned int u23 = cvt_pk_bf16(v2, v3);
      C[(rbase + 0) * E_ + col] = (unsigned short)(u01 & 0xffffu);
      C[(rbase + 1) * E_ + col] = (unsigned short)(u01 >> 16);
      C[(rbase + 2) * E_ + col] = (unsigned short)(u23 & 0xffffu);
      C[(rbase + 3) * E_ + col] = (unsigned short)(u23 >> 16);
    }
  }
}

// ---------------- fused score + softmax + weighted sum ----------------
// One WAVE per batch. q'', k'' are bf16 pre-scaled by 2*log2(e).
// score(q,k) = sum_h wv_h * tanh(q+k) = Wsum - 2*sum_h wv_h / (1 + e^{2(q+k)})
__global__ __launch_bounds__(256, 2)
void attn_fused(const unsigned short* __restrict__ qp,
                const unsigned short* __restrict__ kp,
                const float* __restrict__ keys,
                const float* __restrict__ wv, const float* __restrict__ wvb,
                const int* __restrict__ mask,
                float* __restrict__ out0, float* __restrict__ out1)
{
  const int lane = threadIdx.x & 63;
  const int b    = blockIdx.x * 4 + (threadIdx.x >> 6);

  // per-lane wv slice (h = lane*8 .. +7)
  float wvr[8];
  *(float4*)&wvr[0] = ((const float4*)wv)[lane * 2];
  *(float4*)&wvr[4] = ((const float4*)wv)[lane * 2 + 1];

  // k'' rows -> f32 regs [7][8]
  float kf[NK_][8];
#pragma unroll
  for (int k = 0; k < NK_; ++k){
    u16x8 u = *(const u16x8*)(kp + ((long)b * NK_ + k) * E_ + lane * 8);
#pragma unroll
    for (int j = 0; j < 8; ++j) kf[k][j] = bf2f((unsigned short)u[j]);
  }
  // raw keys -> f32 regs [7][8]
  float kr[NK_][8];
#pragma unroll
  for (int k = 0; k < NK_; ++k){
    const float4* p = (const float4*)(keys + ((long)b * NK_ + k) * E_ + lane * 8);
    *(float4*)&kr[k][0] = p[0];
    *(float4*)&kr[k][4] = p[1];
  }

  // Wsum = sum_h wv_h (butterfly over lanes)
  float wsum = ((wvr[0] + wvr[1]) + (wvr[2] + wvr[3])) + ((wvr[4] + wvr[5]) + (wvr[6] + wvr[7]));
#pragma unroll
  for (int off = 32; off; off >>= 1) wsum += __shfl_xor(wsum, off, 64);

  const float vb = wvb[0];
  float base[NK_];
#pragma unroll
  for (int k = 0; k < NK_; ++k)
    base[k] = (wsum + vb) + (float)mask[b * NK_ + k] * (-1e9f);   // fp32 absorption == ref

  const unsigned short* qrow = qp + (long)b * NQ_ * E_ + lane * 8;
  u16x8 qv = *(const u16x8*)qrow;

  float4* o0 = (float4*)(out0 + (long)b * NQ_ * E_) + lane * 2;
  float*  o1 = out1 + (long)b * (NQ_ * NK_);

  for (int qi = 0; qi < NQ_; ++qi){
    // prefetch next q row (hides HBM latency under this iteration's compute)
    u16x8 qn = qv;
    if (qi < NQ_ - 1) qn = *(const u16x8*)(qrow + (qi + 1) * E_);

    float qf[8];
#pragma unroll
    for (int j = 0; j < 8; ++j) qf[j] = bf2f((unsigned short)qv[j]);
    qv = qn;

    // hot loop: 7 independent accumulator chains
    float acc[NK_];
#pragma unroll
    for (int k = 0; k < NK_; ++k){
      float a = 0.f;
#pragma unroll
      for (int j = 0; j < 8; ++j){
        float x = qf[j] + kf[k][j];                  // 2*log2e*(q+k)
        float e = __builtin_amdgcn_exp2f(x);         // e^{2(q+k)}
        float r = __builtin_amdgcn_rcpf(e + 1.0f);   // sigmoid(-2(q+k))
        a = fmaf(wvr[j], r, a);
      }
      acc[k] = a;
    }
    // 7 independent butterflies (chains pipeline)
#pragma unroll
    for (int k = 0; k < NK_; ++k){
      float a = acc[k];
#pragma unroll
      for (int off = 32; off; off >>= 1) a += __shfl_xor(a, off, 64);
      acc[k] = a;
    }
    // scores + 7-wide softmax (all lanes redundantly, registers only)
    float sc[NK_], mx = -3.4e38f;
#pragma unroll
    for (int k = 0; k < NK_; ++k){ sc[k] = fmaf(-2.f, acc[k], base[k]); mx = fmaxf(mx, sc[k]); }
    float sum = 0.f;
#pragma unroll
    for (int k = 0; k < NK_; ++k){ sc[k] = __expf(sc[k] - mx); sum += sc[k]; }
    const float inv = __builtin_amdgcn_rcpf(sum);
    float wgt[NK_];
#pragma unroll
    for (int k = 0; k < NK_; ++k) wgt[k] = sc[k] * inv;

    // attn_weights: lanes 0..6 write wgt[lane] (branchless select)
    float wsel = wgt[0];
#pragma unroll
    for (int k = 1; k < NK_; ++k) wsel = (lane == k) ? wgt[k] : wsel;
    if (lane < NK_) o1[qi * NK_ + lane] = wsel;

    // attn_out = weights @ raw keys (all in registers)
    float4 lo = {0.f,0.f,0.f,0.f}, hi = {0.f,0.f,0.f,0.f};
#pragma unroll
    for (int k = 0; k < NK_; ++k){
      lo.x = fmaf(wgt[k], kr[k][0], lo.x);
      lo.y = fmaf(wgt[k], kr[k][1], lo.y);
      lo.z = fmaf(wgt[k], kr[k][2], lo.z);
      lo.w = fmaf(wgt[k], kr[k][3], lo.w);
      hi.x = fmaf(wgt[k], kr[k][4], hi.x);
      hi.y = fmaf(wgt[k], kr[k][5], hi.y);
      hi.z = fmaf(wgt[k], kr[k][6], hi.z);
      hi.w = fmaf(wgt[k], kr[k][7], hi.w);
    }
    o0[qi * 128 + 0] = lo;
    o0[qi * 128 + 1] = hi;
  }
}

// ---------------- launcher ----------------
extern "C" void kernel_launch(void* const* d_in, const int* in_sizes, int n_in,
                              void* d_out, int out_size, void* d_ws, size_t ws_size,
                              hipStream_t stream)
{
  const float* queries = (const float*)d_in[0];
  const float* keys    = (const float*)d_in[1];
  const float* wq_w    = (const float*)d_in[2];
  const float* wq_b    = (const float*)d_in[3];
  const float* wk_w    = (const float*)d_in[4];
  const float* wk_b    = (const float*)d_in[5];
  const float* wv_w    = (const float*)d_in[6];
  const float* wv_b    = (const float*)d_in[7];
  const int*   mask    = (const int*)d_in[8];
  (void)in_sizes; (void)n_in; (void)out_size; (void)ws_size;

  float* out0 = (float*)d_out;
  float* out1 = out0 + (long)MQ_ * E_;

  char* ws = (char*)d_ws;
  unsigned short* wqb = (unsigned short*)ws;                       // 512 KB
  unsigned short* wkb = (unsigned short*)(ws + 512 * 512 * 2);     // 512 KB
  unsigned short* qb  = (unsigned short*)(ws + (1 << 20));         // 88.1 MB
  unsigned short* kb  = qb + (size_t)MQ_ * E_;                     // 29.4 MB

  cast_weights<<<dim3(256), dim3(256), 0, stream>>>(wq_w, wk_w, (unsigned int*)wqb, (unsigned int*)wkb);
  gemm_proj<<<dim3((MT1_ + MT2_) * 4), dim3(256), 0, stream>>>(
      queries, keys, wqb, wkb, wq_b, wk_b, qb, kb);
  attn_fused<<<dim3(BS_ / 4), dim3(256), 0, stream>>>(qb, kb, keys, wv_w, wv_b, mask, out0, out1);
}